// Round 1
// baseline (245.065 us; speedup 1.0000x reference)
//
#include <hip/hip_runtime.h>

// SimpleRNN fused kernel for MI355X (gfx950).  B=32768, T=28, I=28, H=128, C=10.
//
// R8: barrier-free, whole-H-per-wave recurrence.
// Each wave owns 16 batch rows for the entire T=28 scan:
//   - W (128x128) resident as 32 bf16 A-fragments in VGPRs (128 regs)
//   - U (128x28, k-padded to 32) as 8 A-fragments (32 regs); bias f32 (32 regs)
//   - S lives in a PRIVATE per-wave LDS slice (double-buffered 2x16x256B = 8KB),
//     XOR-swizzled (byte ^= (row&7)<<4) so both the 8xds_write_b64 (D-packs)
//     and 4xds_read_b128 (B-frags) are bank-balanced.
//   - Step t: 4 ds_read_b128 -> 40 MFMA (8 mt x (1 U + 4 W)) -> 8x tanh4 ->
//     8 ds_write_b64.  NO __syncthreads anywhere; waves fully independent.
//   - x read directly from global (each element exactly once; 112 B per
//     batch-row per step, 16B-aligned), 1-step register prefetch.
// Grid: 2048 waves = 512 blocks x 256 thr -> exactly 2 blocks/CU at <=256 VGPR,
// one residency round, no tail.
// MFMA 16x16x32 bf16 layouts (m89/m91):
//   A[m=lane&15][k=(lane>>4)*8+j]   B[k=(lane>>4)*8+j][n=lane&15]
//   D[(lane>>4)*4+r][lane&15]
// Numerics identical to R7 (same bf16 rounding points, f32 bias/accum,
// Pade(5,4) tanh, epilogue = bf16 S x f32 Vw in f32).

#define T_STEPS 28

typedef __attribute__((ext_vector_type(4))) float f32x4;
typedef __attribute__((ext_vector_type(8))) short short8;

#define MFMA16 __builtin_amdgcn_mfma_f32_16x16x32_bf16

__device__ __forceinline__ unsigned pack2(float lo, float hi) {
#if __has_builtin(__builtin_amdgcn_cvt_pk_bf16_f32)
  auto p = __builtin_amdgcn_cvt_pk_bf16_f32(lo, hi);   // RNE pack, 1 inst
  return __builtin_bit_cast(unsigned, p);
#else
  unsigned a = __builtin_bit_cast(unsigned, lo);
  a += 0x7FFFu + ((a >> 16) & 1u);
  unsigned b = __builtin_bit_cast(unsigned, hi);
  b += 0x7FFFu + ((b >> 16) & 1u);
  return (a >> 16) | (b & 0xFFFF0000u);
#endif
}

__device__ __forceinline__ short8 to_frag(f32x4 a, f32x4 b) {
  union { unsigned u[4]; short8 v; } r;
  r.u[0] = pack2(a[0], a[1]);
  r.u[1] = pack2(a[2], a[3]);
  r.u[2] = pack2(b[0], b[1]);
  r.u[3] = pack2(b[2], b[3]);
  return r.v;
}

// Pade(5,4) tanh, scalar fp32 (best measured, R4): max err ~1.2e-3, den>=945.
__device__ __forceinline__ f32x4 tanh4(f32x4 z) {
  f32x4 x2 = z * z;
  f32x4 p = 945.0f + x2 * (105.0f + x2);
  f32x4 q = 945.0f + x2 * (420.0f + 15.0f * x2);
  f32x4 num = z * p;
  f32x4 r;
#pragma unroll
  for (int i = 0; i < 4; ++i) r[i] = __builtin_amdgcn_rcpf(q[i]);
  f32x4 t = num * r;
#pragma unroll
  for (int i = 0; i < 4; ++i) t[i] = __builtin_amdgcn_fmed3f(t[i], -1.0f, 1.0f);
  return t;
}

__global__ __launch_bounds__(256) void rnn_fused(
    const float* __restrict__ x,  const float* __restrict__ Uw,
    const float* __restrict__ Ub, const float* __restrict__ Ww,
    const float* __restrict__ Wb, const float* __restrict__ Vw,
    const float* __restrict__ Vb, float* __restrict__ out) {
  // per-wave private S buffers: [wave][2 bufs][16 rows][256 B]
  __shared__ __align__(16) char lds[4 * 2 * 16 * 256];

  const int tid  = threadIdx.x;
  const int w    = tid >> 6;
  const int lane = tid & 63;
  const int l15  = lane & 15;
  const int q    = lane >> 4;                  // 0..3
  const int bw   = (blockIdx.x * 4 + w) * 16;  // this wave's batch base

  char* WB       = lds + (w << 13);            // 8 KB slice
  const int rowb = l15 << 8;                   // 256 B per batch-row
  const int swz  = (l15 & 7) << 4;             // XOR-swizzle (bits 4-6)
  const f32x4 zero4 = {0.f, 0.f, 0.f, 0.f};

  // ---- x: direct global, per-lane base (batch l15, i-range q*8..q*8+7) ----
  const float* xp = x + (size_t)(bw + l15) * 784 + q * 8;

  f32x4 xa = *(const f32x4*)xp;                // t=0, i = q*8..+3 (always valid)
  f32x4 xb = zero4;
  if (q < 3) xb = *(const f32x4*)(xp + 4);     // i = q*8+4..+7 (q=3 -> pad 0)

  // ---- persistent weight fragments (identical content in every wave) ----
  short8 wfrag[8][4];   // [mt][kt]: A-rows h=mt*16+l15, k=kt*32+q*8..+7
  short8 ufrag[8];      // [mt], K=32 padded (k>=28 zero)
  f32x4  bias[8];       // Ub+Wb at D rows h = mt*16 + q*4 + r
#pragma unroll
  for (int mt = 0; mt < 8; ++mt) {
    const int h = mt * 16 + l15;
    const float* wp = Ww + h * 128 + q * 8;
#pragma unroll
    for (int kt = 0; kt < 4; ++kt)
      wfrag[mt][kt] =
          to_frag(*(const f32x4*)(wp + kt * 32), *(const f32x4*)(wp + kt * 32 + 4));
    const float* up = Uw + h * 28 + q * 8;
    f32x4 u1 = zero4;
    if (q < 3) u1 = *(const f32x4*)(up + 4);
    ufrag[mt] = to_frag(*(const f32x4*)up, u1);
    const int hb = mt * 16 + q * 4;
    bias[mt] = *(const f32x4*)(Wb + hb) + *(const f32x4*)(Ub + hb);
  }

  // ---- t = 0 (S=0: projection only), write buf0 ----
  {
    short8 xf = to_frag(xa, xb);
    const float* xn = xp + 28;                 // prefetch t=1
    xa = *(const f32x4*)xn;
    xb = zero4;
    if (q < 3) xb = *(const f32x4*)(xn + 4);
#pragma unroll
    for (int mt = 0; mt < 8; ++mt) {
      f32x4 d  = MFMA16(ufrag[mt], xf, bias[mt], 0, 0, 0);
      f32x4 th = tanh4(d);
      uint2 dd; dd.x = pack2(th[0], th[1]); dd.y = pack2(th[2], th[3]);
      *(uint2*)(WB + rowb + ((mt * 32 + q * 8) ^ swz)) = dd;
    }
  }

  // ---- t = 1 .. 27 : barrier-free, per-wave private ping-pong ----
  const float* xn = xp + 56;                   // t=2 onward
#pragma unroll 1
  for (int t = 1; t < T_STEPS; ++t) {
    short8 xf = to_frag(xa, xb);
    if (t < T_STEPS - 1) {                     // prefetch t+1 (uniform branch)
      xa = *(const f32x4*)xn;
      if (q < 3) xb = *(const f32x4*)(xn + 4); else xb = zero4;
      xn += 28;
    }
    const char* rbuf = WB + (((t & 1) ^ 1) << 12);
    char*       wbuf = WB + ((t & 1) << 12);

    short8 sfrag[4];                           // B-frags: S^T[k][b], k=kt*32+q*8..
#pragma unroll
    for (int kt = 0; kt < 4; ++kt)
      sfrag[kt] = *(const short8*)(rbuf + rowb + ((kt * 64 + q * 16) ^ swz));

#pragma unroll
    for (int g = 0; g < 2; ++g) {              // 2 groups of 4 m-tiles
      f32x4 acc[4];
#pragma unroll
      for (int i = 0; i < 4; ++i)
        acc[i] = MFMA16(ufrag[g * 4 + i], xf, bias[g * 4 + i], 0, 0, 0);
#pragma unroll
      for (int kt = 0; kt < 4; ++kt)
#pragma unroll
        for (int i = 0; i < 4; ++i)
          acc[i] = MFMA16(wfrag[g * 4 + i][kt], sfrag[kt], acc[i], 0, 0, 0);
#pragma unroll
      for (int i = 0; i < 4; ++i) {
        f32x4 th = tanh4(acc[i]);
        const int mt = g * 4 + i;
        uint2 dd; dd.x = pack2(th[0], th[1]); dd.y = pack2(th[2], th[3]);
        *(uint2*)(wbuf + rowb + ((mt * 32 + q * 8) ^ swz)) = dd;
      }
    }
  }

  // ---- epilogue: out[b][c] = sum_h S[b][h]*Vw[c][h] + Vb[c] ----
  // Final S in buf[(T-1)&1] = buf1.  lane -> (b = lane&15, c = lane>>4, +4, +8).
  {
    const char* sb   = WB + (((T_STEPS - 1) & 1) << 12);
    const int   br   = lane & 15;
    const int   c0   = lane >> 4;
    const char* srow = sb + (br << 8);
    const int   sw   = (br & 7) << 4;
    for (int c = c0; c < 10; c += 4) {
      const float* vp = Vw + c * 128;
      float a0 = Vb[c];
#pragma unroll
      for (int hh = 0; hh < 128; hh += 2) {
        unsigned d = *(const unsigned*)(srow + ((hh * 2) ^ sw));
        a0 += __builtin_bit_cast(float, d << 16) * vp[hh];
        a0 += __builtin_bit_cast(float, d & 0xFFFF0000u) * vp[hh + 1];
      }
      out[(size_t)(bw + br) * 10 + c] = a0;
    }
  }
}

extern "C" void kernel_launch(void* const* d_in, const int* in_sizes, int n_in,
                              void* d_out, int out_size, void* d_ws, size_t ws_size,
                              hipStream_t stream) {
  const float* x  = (const float*)d_in[0];
  const float* Uw = (const float*)d_in[1];
  const float* Ub = (const float*)d_in[2];
  const float* Ww = (const float*)d_in[3];
  const float* Wb = (const float*)d_in[4];
  const float* Vw = (const float*)d_in[5];
  const float* Vb = (const float*)d_in[6];
  rnn_fused<<<512, 256, 0, stream>>>(x, Uw, Ub, Ww, Wb, Vw, Vb, (float*)d_out);
}